// Round 10
// baseline (71.430 us; speedup 1.0000x reference)
//
#include <hip/hip_runtime.h>

// CalculateSLayer: A = adj[:,:,0]+adj[:,:,1]  (L x L, L=4096)
//   h_in  = A^T @ h   (output 0)
//   h_out = A   @ h   (output 1)
// Round 10: delete the convert pass. Both GEMMs stage RAW fp32 adj via
// global_load_lds (r7/8-proven pipeline) and build fp16 A-fragments at
// ds_read time (channel sum + cvt). houtd reads adj cold (HBM-bound);
// hind runs second and re-reads adj from L3. B from fragment-ordered BF
// (prep). K-split-4 partials + fan-in-4 reduce (r9-verified). No atomics.
// houtd's A-tile reads use the both-sides XOR swizzle (pre-swizzled global
// source slot ^ (row&7), same XOR on ds_read; LDS dest stays linear).

typedef _Float16 half8 __attribute__((ext_vector_type(8)));
typedef float f32x4 __attribute__((ext_vector_type(4)));

#define LL 4096
#define DD 150
#define LLDD (LL * DD)                    // 614400
#define BF_BYTES ((size_t)10 * 128 * 512 * 2)   // 1310720

// BF unit (nt, S): 64 lanes x 8 halfs; lane (r=l&15, g=l>>4), elem e holds
// B[k = S*32+g*8+e][n = nt*16+r] = h[k][nt*16+r]  (verified rounds 5-9).
__global__ __launch_bounds__(256) void prep_kernel(const float* __restrict__ h,
                                                   _Float16* __restrict__ BF) {
    const int lg = blockIdx.x * 256 + threadIdx.x;   // 81920 lane-units
    const int u = lg >> 6, l = lg & 63;
    const int nt = u >> 7, S = u & 127;
    const int r = l & 15, g = l >> 4;
    const int d = nt * 16 + r;
    const int j0 = S * 32 + g * 8;
    half8 v;
#pragma unroll
    for (int e = 0; e < 8; ++e)
        v[e] = (d < DD) ? (_Float16)h[(size_t)(j0 + e) * DD + d] : (_Float16)0.0f;
    *(half8*)(BF + (size_t)lg * 8) = v;
}

// h_out direct. Block: 32 rows (i0..i0+31), K(j)-slice 1024. 4 waves:
// wave (m = w&1 -> 16-row tile, nh = w>>1 -> 5 n-tiles). 16 chunks of 64 j.
// LDS chunk: A raw 16 KB [rl 0..31][jh 0..1][slot 0..15][16B], slot holds
// global j-slot (slot ^ (rl&7)) [XOR pre-swizzle]; B 20 KB units (q*2+s).
__global__ __launch_bounds__(256, 2) void houtd_kernel(const float* __restrict__ adj,
                                                       const _Float16* __restrict__ BF,
                                                       float* __restrict__ P) {
    __shared__ __align__(16) unsigned char lds[2][36 * 1024];   // 73728 B
    const int tid = threadIdx.x;
    const int wave = tid >> 6, lane = tid & 63;
    const int r = lane & 15, g = lane >> 4;
    const int o = (blockIdx.x & 7) * 64 + (blockIdx.x >> 3);   // bijective XCD swizzle
    const int ks = o & 3;
    const int Rb = o >> 2;             // 0..127
    const int i0 = Rb * 32;
    const int jbase = ks * 1024;
    const int m = wave & 1, nh = wave >> 1;
    const char* adjc = (const char*)adj;

    f32x4 acc[5];
#pragma unroll
    for (int q = 0; q < 5; ++q) acc[q] = (f32x4){0.f, 0.f, 0.f, 0.f};

    // staging: unified list of 36 1-KB loads; this wave does 9.
    //  idx<16: A instr k: lane -> rl = k*2 + (lane>>5), jh = (lane>>4)&1,
    //          slot = lane&15; LDS byte k*1024+lane*16 (== rl*512+jh*256+slot*16)
    //          src: adj[(i0+rl)][j = cj + jh*32 + 2*(slot^(rl&7)) .. +2][ch0..1]
    //  idx>=16: B unit u = idx-16: q = u>>1, s = u&1; src BF unit (q, Sg)
#define HOUT_STAGE(buf, cj, Sg0)                                                     \
    {                                                                                \
        _Pragma("unroll")                                                            \
        for (int kk = 0; kk < 9; ++kk) {                                             \
            const int idx = wave * 9 + kk;                                           \
            if (idx < 16) {                                                          \
                const int rl = idx * 2 + (lane >> 5);                                \
                const int jh = (lane >> 4) & 1;                                      \
                const int slot = lane & 15;                                          \
                const char* src = adjc + (size_t)(i0 + rl) * 32768                   \
                                  + (size_t)(cj + jh * 32) * 8                       \
                                  + ((slot ^ (rl & 7)) << 4);                        \
                __builtin_amdgcn_global_load_lds(                                    \
                    (const __attribute__((address_space(1))) void*)src,              \
                    (__attribute__((address_space(3))) void*)(&lds[buf][idx * 1024   \
                        + lane * 16]), 16, 0, 0);                                    \
            } else {                                                                 \
                const int u = idx - 16;                                              \
                const _Float16* src = BF + ((size_t)(u >> 1) * 128 + Sg0 + (u & 1))  \
                                      * 512 + lane * 8;                              \
                __builtin_amdgcn_global_load_lds(                                    \
                    (const __attribute__((address_space(1))) void*)src,              \
                    (__attribute__((address_space(3))) void*)(&lds[buf][16384        \
                        + u * 1024 + lane * 16]), 16, 0, 0);                         \
            }                                                                        \
        }                                                                            \
    }

    HOUT_STAGE(0, jbase, (jbase >> 5))
    __syncthreads();

    const int row = m * 16 + r;        // A row within 32-row tile
    for (int c = 0; c < 16; ++c) {
        const int buf = c & 1;
        if (c < 15) HOUT_STAGE(buf ^ 1, jbase + (c + 1) * 64, ((jbase >> 5) + (c + 1) * 2))
#pragma unroll
        for (int s = 0; s < 2; ++s) {
            half8 a;
#pragma unroll
            for (int t = 0; t < 4; ++t) {
                const float4 f = *(const float4*)(&lds[buf][row * 512 + s * 256
                                      + (((g * 4 + t) ^ (row & 7)) << 4)]);
                a[2 * t]     = (_Float16)(f.x + f.y);
                a[2 * t + 1] = (_Float16)(f.z + f.w);
            }
#pragma unroll
            for (int q = 0; q < 5; ++q) {
                const half8 b = *(const half8*)(&lds[buf][16384
                                    + (((nh * 5 + q) << 1) + s) * 1024 + lane * 16]);
                acc[q] = __builtin_amdgcn_mfma_f32_16x16x32_f16(a, b, acc[q], 0, 0, 0);
            }
        }
        __syncthreads();
    }
#undef HOUT_STAGE

    // D layout: row = g*4+u, col = r (verified rounds 1-9). h_out slices 0..3.
    float* dst = P + (size_t)ks * LLDD;
    const int orow = i0 + m * 16 + g * 4;
#pragma unroll
    for (int q = 0; q < 5; ++q) {
        const int d = (nh * 5 + q) * 16 + r;
        if (d < DD) {
#pragma unroll
            for (int u = 0; u < 4; ++u)
                dst[(size_t)(orow + u) * DD + d] = acc[q][u];
        }
    }
}

// h_in direct. Block: 32 cols (j0..j0+31), K(i)-slice 1024. Same wave map.
// 16 chunks of 64 i-rows. LDS chunk: A raw 16 KB [il 0..63][slot 0..15][16B]
// (no swizzle; frag reads are i-strided b64, ~4-way alias); B 20 KB.
__global__ __launch_bounds__(256, 2) void hind_kernel(const float* __restrict__ adj,
                                                      const _Float16* __restrict__ BF,
                                                      float* __restrict__ P) {
    __shared__ __align__(16) unsigned char lds[2][36 * 1024];   // 73728 B
    const int tid = threadIdx.x;
    const int wave = tid >> 6, lane = tid & 63;
    const int r = lane & 15, g = lane >> 4;
    const int o = (blockIdx.x & 7) * 64 + (blockIdx.x >> 3);   // bijective XCD swizzle
    const int ks = o & 3;
    const int Cb = o >> 2;             // 0..127
    const int j0 = Cb * 32;
    const int ibase = ks * 1024;
    const int m = wave & 1, nh = wave >> 1;
    const char* adjc = (const char*)adj;

    f32x4 acc[5];
#pragma unroll
    for (int q = 0; q < 5; ++q) acc[q] = (f32x4){0.f, 0.f, 0.f, 0.f};

    //  idx<16: A instr k: lane -> il = k*4 + (lane>>4), slot = lane&15
    //          LDS byte k*1024+lane*16 == il*256 + slot*16
    //          src: adj[ci + il][j0 + 2*slot .. +2][ch0..1]
#define HIN_STAGE(buf, ci, Sg0)                                                      \
    {                                                                                \
        _Pragma("unroll")                                                            \
        for (int kk = 0; kk < 9; ++kk) {                                             \
            const int idx = wave * 9 + kk;                                           \
            if (idx < 16) {                                                          \
                const int il = idx * 4 + (lane >> 4);                                \
                const int slot = lane & 15;                                          \
                const char* src = adjc + (size_t)(ci + il) * 32768                   \
                                  + (size_t)j0 * 8 + (slot << 4);                    \
                __builtin_amdgcn_global_load_lds(                                    \
                    (const __attribute__((address_space(1))) void*)src,              \
                    (__attribute__((address_space(3))) void*)(&lds[buf][idx * 1024   \
                        + lane * 16]), 16, 0, 0);                                    \
            } else {                                                                 \
                const int u = idx - 16;                                              \
                const _Float16* src = BF + ((size_t)(u >> 1) * 128 + Sg0 + (u & 1))  \
                                      * 512 + lane * 8;                              \
                __builtin_amdgcn_global_load_lds(                                    \
                    (const __attribute__((address_space(1))) void*)src,              \
                    (__attribute__((address_space(3))) void*)(&lds[buf][16384        \
                        + u * 1024 + lane * 16]), 16, 0, 0);                         \
            }                                                                        \
        }                                                                            \
    }

    HIN_STAGE(0, ibase, (ibase >> 5))
    __syncthreads();

    const int jl = m * 16 + r;         // A^T row = adj column
    const int jslotbyte = (m * 8 + (r >> 1)) * 16 + (r & 1) * 8;
    for (int c = 0; c < 16; ++c) {
        const int buf = c & 1;
        if (c < 15) HIN_STAGE(buf ^ 1, ibase + (c + 1) * 64, ((ibase >> 5) + (c + 1) * 2))
#pragma unroll
        for (int s = 0; s < 2; ++s) {
            half8 a;
#pragma unroll
            for (int e = 0; e < 8; ++e) {
                const float2 f = *(const float2*)(&lds[buf][(s * 32 + g * 8 + e) * 256
                                      + jslotbyte]);
                a[e] = (_Float16)(f.x + f.y);
            }
#pragma unroll
            for (int q = 0; q < 5; ++q) {
                const half8 b = *(const half8*)(&lds[buf][16384
                                    + (((nh * 5 + q) << 1) + s) * 1024 + lane * 16]);
                acc[q] = __builtin_amdgcn_mfma_f32_16x16x32_f16(a, b, acc[q], 0, 0, 0);
            }
        }
        __syncthreads();
    }
#undef HIN_STAGE

    // h_in slices 4..7.
    float* dst = P + (size_t)(4 + ks) * LLDD;
    const int orow = j0 + m * 16 + g * 4;
#pragma unroll
    for (int q = 0; q < 5; ++q) {
        const int d = (nh * 5 + q) * 16 + r;
        if (d < DD) {
#pragma unroll
            for (int u = 0; u < 4; ++u)
                dst[(size_t)(orow + u) * DD + d] = acc[q][u];
        }
    }
}

// out[0:LLDD) = h_in = sum P[4..7]; out[LLDD:2*LLDD) = h_out = sum P[0..3]
__global__ __launch_bounds__(256) void reduce_kernel(const float* __restrict__ P,
                                                     float* __restrict__ out) {
    const int idx = blockIdx.x * 256 + threadIdx.x;
    const int nv = LLDD / 4;
    const float4* p = (const float4*)P;
    const float4* src = (idx < nv) ? (p + (size_t)4 * nv) : p;
    const int e = (idx < nv) ? idx : idx - nv;
    const float4 a = src[e], b = src[e + nv], c = src[e + 2 * nv], d = src[e + 3 * nv];
    float4 s;
    s.x = (a.x + b.x) + (c.x + d.x);
    s.y = (a.y + b.y) + (c.y + d.y);
    s.z = (a.z + b.z) + (c.z + d.z);
    s.w = (a.w + b.w) + (c.w + d.w);
    ((float4*)out)[idx] = s;
}

extern "C" void kernel_launch(void* const* d_in, const int* in_sizes, int n_in,
                              void* d_out, int out_size, void* d_ws, size_t ws_size,
                              hipStream_t stream) {
    const float* adj = (const float*)d_in[0];   // [4096, 4096, 2] fp32
    const float* h   = (const float*)d_in[1];   // [4096, 150] fp32
    float* out = (float*)d_out;
    _Float16* BF = (_Float16*)d_ws;                 // 1.31 MB
    float* P = (float*)((char*)d_ws + BF_BYTES);    // 19.66 MB (8 slices)

    hipLaunchKernelGGL(prep_kernel,  dim3(320), dim3(256), 0, stream, h, BF);
    hipLaunchKernelGGL(houtd_kernel, dim3(512), dim3(256), 0, stream, adj, BF, P);
    hipLaunchKernelGGL(hind_kernel,  dim3(512), dim3(256), 0, stream, adj, BF, P);
    hipLaunchKernelGGL(reduce_kernel, dim3(2 * LLDD / 4 / 256), dim3(256), 0, stream,
                       P, out);
}

// Round 11
// 69.249 us; speedup vs baseline: 1.0315x; 1.0315x over previous
//
#include <hip/hip_runtime.h>

// CalculateSLayer: A = adj[:,:,0]+adj[:,:,1]  (L x L, L=4096)
//   h_in  = A^T @ h   (output 0)
//   h_out = A   @ h   (output 1)
// Round 11: r8 (best, 61.4us) + direct output accumulation. The gemm's two
// K-slices unsafeAtomicAdd into out (fan-in 2; prep zeroes out each call),
// deleting the P buffer and reduce kernel. convert + gemm K-loop are
// byte-identical to round 8 (proven).

typedef _Float16 half8 __attribute__((ext_vector_type(8)));
typedef float f32x4 __attribute__((ext_vector_type(4)));

#define LL 4096
#define DD 150
#define LLDD (LL * DD)                    // 614400
#define BF_BYTES ((size_t)10 * 128 * 512 * 2)   // 1310720
#define TS 72                             // convert LDS tile row stride (halfs)

// BF unit (nt, S): 64 lanes x 8 halfs; lane (r=l&15, g=l>>4), elem e holds
// B[k = S*32+g*8+e][n = nt*16+r] = h[k][nt*16+r]  (verified rounds 5-10).
// Also zeroes out[] (atomic-accumulate target, re-zeroed every call).
__global__ __launch_bounds__(256) void prep_kernel(const float* __restrict__ h,
                                                   _Float16* __restrict__ BF,
                                                   float* __restrict__ out) {
    const int idx = blockIdx.x * 256 + threadIdx.x;   // grid 1280*256 = 327680
    if (idx < 2 * LLDD / 4) ((float4*)out)[idx] = (float4){0.f, 0.f, 0.f, 0.f};
    if (idx < 81920) {
        const int u = idx >> 6, l = idx & 63;
        const int nt = u >> 7, S = u & 127;
        const int r = l & 15, g = l >> 4;
        const int d = nt * 16 + r;
        const int j0 = S * 32 + g * 8;
        half8 v;
#pragma unroll
        for (int e = 0; e < 8; ++e)
            v[e] = (d < DD) ? (_Float16)h[(size_t)(j0 + e) * DD + d] : (_Float16)0.0f;
        *(half8*)(BF + (size_t)idx * 8) = v;
    }
}

// Streams one 64x64 tile of A: coalesced adj read, fp16-sum, emits A-operand
// fragment units (verified rounds 1-10). Unit (T,S) elem: A[T*16+r][S*32+g*8+e].
__global__ __launch_bounds__(256) void convert_kernel(const float* __restrict__ adj,
                                                      _Float16* __restrict__ AF,
                                                      _Float16* __restrict__ ATF) {
    __shared__ _Float16 T64[64][TS];   // 9216 B
    const int tid = threadIdx.x;
    const int bi = blockIdx.x >> 6;
    const int bj = blockIdx.x & 63;
    const float4* adj4 = (const float4*)adj;

#pragma unroll
    for (int it = 0; it < 8; ++it) {
        const int vidx = it * 256 + tid;
        const int il = vidx >> 5, jq = vidx & 31;
        const float4 v = adj4[(size_t)(bi * 64 + il) * 2048 + bj * 32 + jq];
        union { _Float16 h[2]; unsigned u; } p;
        p.h[0] = (_Float16)(v.x + v.y);
        p.h[1] = (_Float16)(v.z + v.w);
        *(unsigned*)((char*)&T64[il][0] + jq * 4) = p.u;
    }
    __syncthreads();

    const int wave = tid >> 6, lane = tid & 63;
    const int r = lane & 15, g = lane >> 4;
#pragma unroll
    for (int c = 0; c < 2; ++c) {
        const half8 va = *(const half8*)((const char*)&T64[wave * 16 + r][0]
                                         + (c * 32 + g * 8) * 2);
        *(half8*)(AF + ((size_t)(bi * 4 + wave) * 128 + (bj * 2 + c)) * 512
                  + lane * 8) = va;
        half8 vt;
#pragma unroll
        for (int e = 0; e < 8; ++e) vt[e] = T64[c * 32 + g * 8 + e][wave * 16 + r];
        *(half8*)(ATF + ((size_t)(bj * 4 + wave) * 128 + (bi * 2 + c)) * 512
                  + lane * 8) = vt;
    }
}

// gemm (m97 pattern, round-7/8-verified). Block: 4 waves; owns output half,
// 4 M-tiles (wave w -> T0+w), 5 n-tiles (nh half), K-slice 2048 (64 S-steps,
// 16 chunks of 4). Chunk = 36 LDS units of 1 KB: u<16 A(T=u>>2, s=u&3),
// u>=16 B(nt=(u-16)>>2, s=(u-16)&3). Stage via global_load_lds width 16.
// Epilogue: unsafeAtomicAdd into out (fan-in 2 across ks slices).
__global__ __launch_bounds__(256, 2) void gemm_kernel(const _Float16* __restrict__ AF,
                                                      const _Float16* __restrict__ ATF,
                                                      const _Float16* __restrict__ BF,
                                                      float* __restrict__ out) {
    __shared__ __align__(16) _Float16 lds[2][36 * 512];   // 73728 B
    const int tid = threadIdx.x;
    const int wave = tid >> 6, lane = tid & 63;
    const int r = lane & 15, g = lane >> 4;

    // bijective XCD swizzle (nwg=512, %8==0): contiguous 64-chunk per XCD
    const int o = (blockIdx.x & 7) * 64 + (blockIdx.x >> 3);
    const int ks = o & 1;              // K-split slice (of 2)
    const int nh = (o >> 1) & 1;       // n-half: nt 0..4 or 5..9
    const int Mblk = (o >> 2) & 63;
    const int isIn = (o >> 8) & 1;     // 0: h_out (AF), 1: h_in (ATF)

    const _Float16* Asrc = isIn ? ATF : AF;
    const int T0 = Mblk * 4;
    const int Sbase = ks * 64;

    f32x4 acc[5];
#pragma unroll
    for (int q = 0; q < 5; ++q) acc[q] = (f32x4){0.f, 0.f, 0.f, 0.f};

    // ---- stage chunk 0 ----
    {
        const int chunkS = Sbase;
#pragma unroll
        for (int k = 0; k < 9; ++k) {
            const int u = wave * 9 + k;
            const _Float16* src;
            if (u < 16) {
                src = Asrc + ((size_t)(T0 + (u >> 2)) * 128 + chunkS + (u & 3)) * 512;
            } else {
                const int v = u - 16;
                src = BF + ((size_t)(nh * 5 + (v >> 2)) * 128 + chunkS + (v & 3)) * 512;
            }
            __builtin_amdgcn_global_load_lds(
                (const __attribute__((address_space(1))) void*)(src + lane * 8),
                (__attribute__((address_space(3))) void*)(&lds[0][u * 512]),
                16, 0, 0);
        }
    }
    __syncthreads();

    for (int c = 0; c < 16; ++c) {
        const int buf = c & 1;
        if (c < 15) {   // issue next-chunk stage BEFORE compute
            const int chunkS = Sbase + (c + 1) * 4;
#pragma unroll
            for (int k = 0; k < 9; ++k) {
                const int u = wave * 9 + k;
                const _Float16* src;
                if (u < 16) {
                    src = Asrc + ((size_t)(T0 + (u >> 2)) * 128 + chunkS + (u & 3)) * 512;
                } else {
                    const int v = u - 16;
                    src = BF + ((size_t)(nh * 5 + (v >> 2)) * 128 + chunkS + (v & 3)) * 512;
                }
                __builtin_amdgcn_global_load_lds(
                    (const __attribute__((address_space(1))) void*)(src + lane * 8),
                    (__attribute__((address_space(3))) void*)(&lds[buf ^ 1][u * 512]),
                    16, 0, 0);
            }
        }
        // ---- compute chunk c from lds[buf] ----
        half8 a[4];
#pragma unroll
        for (int s = 0; s < 4; ++s)
            a[s] = *(const half8*)(&lds[buf][(wave * 4 + s) * 512 + lane * 8]);
#pragma unroll
        for (int q = 0; q < 5; ++q)
#pragma unroll
            for (int s = 0; s < 4; ++s) {
                const half8 b = *(const half8*)(&lds[buf][(16 + q * 4 + s) * 512
                                                          + lane * 8]);
                acc[q] = __builtin_amdgcn_mfma_f32_16x16x32_f16(a[s], b, acc[q], 0, 0, 0);
            }
        __syncthreads();   // drains this wave's gloads; releases buf for overwrite
    }

    // D layout: row = g*4+u, col = r (verified rounds 1-10).
    // Direct accumulate: h_in -> out[0:LLDD), h_out -> out[LLDD:2*LLDD).
    float* dst = out + (isIn ? 0 : (size_t)LLDD);
    const int row = (T0 + wave) * 16 + g * 4;
#pragma unroll
    for (int q = 0; q < 5; ++q) {
        const int d = (nh * 5 + q) * 16 + r;
        if (d < DD) {
#pragma unroll
            for (int u = 0; u < 4; ++u)
                unsafeAtomicAdd(&dst[(size_t)(row + u) * DD + d], acc[q][u]);
        }
    }
}

extern "C" void kernel_launch(void* const* d_in, const int* in_sizes, int n_in,
                              void* d_out, int out_size, void* d_ws, size_t ws_size,
                              hipStream_t stream) {
    const float* adj = (const float*)d_in[0];   // [4096, 4096, 2] fp32
    const float* h   = (const float*)d_in[1];   // [4096, 150] fp32
    float* out = (float*)d_out;
    _Float16* BF = (_Float16*)d_ws;                    // 1.31 MB
    _Float16* AF = (_Float16*)((char*)d_ws + BF_BYTES);// 33.55 MB
    _Float16* ATF = AF + (size_t)16777216;             // 33.55 MB

    hipLaunchKernelGGL(prep_kernel, dim3(1280), dim3(256), 0, stream, h, BF, out);
    hipLaunchKernelGGL(convert_kernel, dim3(4096), dim3(256), 0, stream, adj, AF, ATF);
    hipLaunchKernelGGL(gemm_kernel, dim3(512), dim3(256), 0, stream, AF, ATF, BF, out);
}

// Round 12
// 61.660 us; speedup vs baseline: 1.1584x; 1.1231x over previous
//
#include <hip/hip_runtime.h>

// CalculateSLayer: A = adj[:,:,0]+adj[:,:,1]  (L x L, L=4096)
//   h_in  = A^T @ h   (output 0)
//   h_out = A   @ h   (output 1)
// Round 12: r8 (proven best, 61.4us) with ONE change: the gemm K-loop's
// __syncthreads (which drains vmcnt(0), killing the issued-early prefetch)
// is replaced by counted s_waitcnt vmcnt(9) + raw s_barrier pairs (catalog
// T4). Each wave issues exactly 9 global_load_lds per chunk, so vmcnt(9)
// retires exactly the previous chunk's loads; barrier1 publishes staging,
// barrier2 protects the buffer being overwritten next. sched_barrier(0)
// fences stop hipcc reordering across the raw barriers (rule #18).
// prep/convert/reduce byte-identical to round 8.

typedef _Float16 half8 __attribute__((ext_vector_type(8)));
typedef float f32x4 __attribute__((ext_vector_type(4)));

#define LL 4096
#define DD 150
#define LLDD (LL * DD)                    // 614400
#define BF_BYTES ((size_t)10 * 128 * 512 * 2)   // 1310720
#define P_BYTES ((size_t)4 * LLDD * 4)          // 9830400 (4 slices)
#define TS 72                             // convert LDS tile row stride (halfs)

// BF unit (nt, S): 64 lanes x 8 halfs; lane (r=l&15, g=l>>4), elem e holds
// B[k = S*32+g*8+e][n = nt*16+r] = h[k][nt*16+r]  (verified rounds 5-11).
__global__ __launch_bounds__(256) void prep_kernel(const float* __restrict__ h,
                                                   _Float16* __restrict__ BF) {
    const int lg = blockIdx.x * 256 + threadIdx.x;   // 81920 lane-units
    const int u = lg >> 6, l = lg & 63;
    const int nt = u >> 7, S = u & 127;
    const int r = l & 15, g = l >> 4;
    const int d = nt * 16 + r;
    const int j0 = S * 32 + g * 8;
    half8 v;
#pragma unroll
    for (int e = 0; e < 8; ++e)
        v[e] = (d < DD) ? (_Float16)h[(size_t)(j0 + e) * DD + d] : (_Float16)0.0f;
    *(half8*)(BF + (size_t)lg * 8) = v;
}

// Streams one 64x64 tile of A: coalesced adj read, fp16-sum, emits A-operand
// fragment units (verified rounds 1-11). Unit (T,S) elem: A[T*16+r][S*32+g*8+e].
__global__ __launch_bounds__(256) void convert_kernel(const float* __restrict__ adj,
                                                      _Float16* __restrict__ AF,
                                                      _Float16* __restrict__ ATF) {
    __shared__ _Float16 T64[64][TS];   // 9216 B
    const int tid = threadIdx.x;
    const int bi = blockIdx.x >> 6;
    const int bj = blockIdx.x & 63;
    const float4* adj4 = (const float4*)adj;

#pragma unroll
    for (int it = 0; it < 8; ++it) {
        const int vidx = it * 256 + tid;
        const int il = vidx >> 5, jq = vidx & 31;
        const float4 v = adj4[(size_t)(bi * 64 + il) * 2048 + bj * 32 + jq];
        union { _Float16 h[2]; unsigned u; } p;
        p.h[0] = (_Float16)(v.x + v.y);
        p.h[1] = (_Float16)(v.z + v.w);
        *(unsigned*)((char*)&T64[il][0] + jq * 4) = p.u;
    }
    __syncthreads();

    const int wave = tid >> 6, lane = tid & 63;
    const int r = lane & 15, g = lane >> 4;
#pragma unroll
    for (int c = 0; c < 2; ++c) {
        const half8 va = *(const half8*)((const char*)&T64[wave * 16 + r][0]
                                         + (c * 32 + g * 8) * 2);
        *(half8*)(AF + ((size_t)(bi * 4 + wave) * 128 + (bj * 2 + c)) * 512
                  + lane * 8) = va;
        half8 vt;
#pragma unroll
        for (int e = 0; e < 8; ++e) vt[e] = T64[c * 32 + g * 8 + e][wave * 16 + r];
        *(half8*)(ATF + ((size_t)(bj * 4 + wave) * 128 + (bi * 2 + c)) * 512
                  + lane * 8) = vt;
    }
}

// gemm (r8 geometry). Block: 4 waves; owns output half, 4 M-tiles (wave w ->
// T0+w), 5 n-tiles (nh half), K-slice 2048 (64 S-steps, 16 chunks of 4).
// Chunk = 36 LDS units of 1 KB: u<16 A(T=u>>2, s=u&3), u>=16 B(nt=(u-16)>>2,
// s=(u-16)&3). Counted-vmcnt pipeline: stage(c+1); vmcnt(9); bar; compute(c);
// bar. Prefetched loads stay in flight across barriers (no vmcnt(0) drain).
__global__ __launch_bounds__(256, 2) void gemm_kernel(const _Float16* __restrict__ AF,
                                                      const _Float16* __restrict__ ATF,
                                                      const _Float16* __restrict__ BF,
                                                      float* __restrict__ P) {
    __shared__ __align__(16) _Float16 lds[2][36 * 512];   // 73728 B
    const int tid = threadIdx.x;
    const int wave = tid >> 6, lane = tid & 63;
    const int r = lane & 15, g = lane >> 4;

    // bijective XCD swizzle (nwg=512, %8==0): contiguous 64-chunk per XCD
    const int o = (blockIdx.x & 7) * 64 + (blockIdx.x >> 3);
    const int ks = o & 1;              // K-split slice (of 2)
    const int nh = (o >> 1) & 1;       // n-half: nt 0..4 or 5..9
    const int Mblk = (o >> 2) & 63;
    const int isIn = (o >> 8) & 1;     // 0: h_out (AF), 1: h_in (ATF)

    const _Float16* Asrc = isIn ? ATF : AF;
    const int T0 = Mblk * 4;
    const int Sbase = ks * 64;

    f32x4 acc[5];
#pragma unroll
    for (int q = 0; q < 5; ++q) acc[q] = (f32x4){0.f, 0.f, 0.f, 0.f};

    // 9 global_load_lds per wave per chunk (u = wave*9 .. wave*9+8)
#define STAGE(buf, chunkS)                                                           \
    {                                                                                \
        _Pragma("unroll")                                                            \
        for (int k = 0; k < 9; ++k) {                                                \
            const int u = wave * 9 + k;                                              \
            const _Float16* src;                                                     \
            if (u < 16) {                                                            \
                src = Asrc + ((size_t)(T0 + (u >> 2)) * 128 + (chunkS) + (u & 3))    \
                      * 512;                                                         \
            } else {                                                                 \
                const int v = u - 16;                                                \
                src = BF + ((size_t)(nh * 5 + (v >> 2)) * 128 + (chunkS) + (v & 3))  \
                      * 512;                                                         \
            }                                                                        \
            __builtin_amdgcn_global_load_lds(                                        \
                (const __attribute__((address_space(1))) void*)(src + lane * 8),     \
                (__attribute__((address_space(3))) void*)(&lds[buf][u * 512]),       \
                16, 0, 0);                                                           \
        }                                                                            \
    }

#define COMPUTE(buf)                                                                 \
    {                                                                                \
        half8 a[4];                                                                  \
        _Pragma("unroll")                                                            \
        for (int s = 0; s < 4; ++s)                                                  \
            a[s] = *(const half8*)(&lds[buf][(wave * 4 + s) * 512 + lane * 8]);      \
        _Pragma("unroll")                                                            \
        for (int q = 0; q < 5; ++q)                                                  \
            _Pragma("unroll")                                                        \
            for (int s = 0; s < 4; ++s) {                                            \
                const half8 b = *(const half8*)(&lds[buf][(16 + q * 4 + s) * 512     \
                                                          + lane * 8]);              \
                acc[q] = __builtin_amdgcn_mfma_f32_16x16x32_f16(a[s], b, acc[q],     \
                                                                0, 0, 0);            \
            }                                                                        \
    }

    STAGE(0, Sbase)
    for (int c = 0; c < 15; ++c) {
        const int buf = c & 1;
        STAGE(buf ^ 1, Sbase + (c + 1) * 4)
        asm volatile("s_waitcnt vmcnt(9)" ::: "memory");   // stage(c) landed (this wave)
        __builtin_amdgcn_sched_barrier(0);
        __builtin_amdgcn_s_barrier();                       // stage(c) landed (all waves)
        __builtin_amdgcn_sched_barrier(0);
        COMPUTE(buf)
        __builtin_amdgcn_sched_barrier(0);
        __builtin_amdgcn_s_barrier();                       // reads of buf done (all waves)
        __builtin_amdgcn_sched_barrier(0);
    }
    asm volatile("s_waitcnt vmcnt(0)" ::: "memory");        // stage(15) landed
    __builtin_amdgcn_sched_barrier(0);
    __builtin_amdgcn_s_barrier();
    __builtin_amdgcn_sched_barrier(0);
    COMPUTE(1)
#undef STAGE
#undef COMPUTE

    // D layout: row = g*4+u, col = r (verified rounds 1-11)
    float* dst = P + (size_t)(isIn * 2 + ks) * LLDD;
    const int row = (T0 + wave) * 16 + g * 4;
#pragma unroll
    for (int q = 0; q < 5; ++q) {
        const int d = (nh * 5 + q) * 16 + r;
        if (d < DD) {
#pragma unroll
            for (int u = 0; u < 4; ++u)
                dst[(size_t)(row + u) * DD + d] = acc[q][u];
        }
    }
}

// out[0:LLDD) = h_in = P[2]+P[3]; out[LLDD:2*LLDD) = h_out = P[0]+P[1]
__global__ __launch_bounds__(256) void reduce_kernel(const float* __restrict__ P,
                                                     float* __restrict__ out) {
    const int idx = blockIdx.x * 256 + threadIdx.x;   // over 2*LLDD/4 float4s
    const int nv = LLDD / 4;
    const float4* p = (const float4*)P;
    const float4* src = (idx < nv) ? (p + (size_t)2 * nv) : p;   // h_in : h_out
    const int e = (idx < nv) ? idx : idx - nv;
    const float4 a = src[e], b = src[e + nv];
    float4 s;
    s.x = a.x + b.x;
    s.y = a.y + b.y;
    s.z = a.z + b.z;
    s.w = a.w + b.w;
    ((float4*)out)[idx] = s;
}

extern "C" void kernel_launch(void* const* d_in, const int* in_sizes, int n_in,
                              void* d_out, int out_size, void* d_ws, size_t ws_size,
                              hipStream_t stream) {
    const float* adj = (const float*)d_in[0];   // [4096, 4096, 2] fp32
    const float* h   = (const float*)d_in[1];   // [4096, 150] fp32
    float* out = (float*)d_out;
    _Float16* BF = (_Float16*)d_ws;                               // 1.31 MB
    float* P = (float*)((char*)d_ws + BF_BYTES);                  // 9.83 MB
    _Float16* AF = (_Float16*)((char*)d_ws + BF_BYTES + P_BYTES); // 33.55 MB
    _Float16* ATF = AF + (size_t)16777216;                        // 33.55 MB

    hipLaunchKernelGGL(prep_kernel, dim3(320), dim3(256), 0, stream, h, BF);
    hipLaunchKernelGGL(convert_kernel, dim3(4096), dim3(256), 0, stream, adj, AF, ATF);
    hipLaunchKernelGGL(gemm_kernel, dim3(512), dim3(256), 0, stream, AF, ATF, BF, P);
    hipLaunchKernelGGL(reduce_kernel, dim3(2 * LLDD / 4 / 256), dim3(256), 0, stream,
                       P, out);
}